// Round 1
// baseline (428.452 us; speedup 1.0000x reference)
//
#include <hip/hip_runtime.h>
#include <math.h>

#define HW_   128
#define CIN_  64
#define IMG_  (HW_ * HW_)       // 16384

// ws layout (bytes):
//   [0,        147456)  wT_conv [576][64]  : wT_conv[k][o] = w_conv[o][k], k = c*9+j
//   [147456,   221184)  wT_off  [576][32]  : wT_off[c*9+kk][oc] = w_off[oc][c][kh][kw]
//   [221184, 14376960)  offbuf  [8][27][128][128] : o1 (ch 0-8), o2 (9-17), sigmoid(mask) (18-26)

__global__ __launch_bounds__(256) void xpose_w(const float* __restrict__ w_off,
                                               const float* __restrict__ w_conv,
                                               float* __restrict__ wT_conv,
                                               float* __restrict__ wT_off) {
  int t = blockIdx.x * 256 + threadIdx.x;
  if (t < 576 * 64) {
    int k = t >> 6, o = t & 63;
    wT_conv[t] = w_conv[o * 576 + k];
  }
  if (t < 576 * 27) {
    int row = t / 27, oc = t - row * 27;
    wT_off[row * 32 + oc] = w_off[oc * 576 + row];
  }
}

__global__ __launch_bounds__(256) void off_conv(const float* __restrict__ x,
                                                const float* __restrict__ wT_off,
                                                const float* __restrict__ b_off,
                                                float* __restrict__ offbuf) {
  int t = blockIdx.x * 256 + threadIdx.x;
  int wi = t & 127, hi = (t >> 7) & 127, bi = t >> 14;

  float acc[27];
#pragma unroll
  for (int i = 0; i < 27; ++i) acc[i] = 0.f;

  const float* xb = x + bi * (CIN_ * IMG_);

  // 3x3 neighborhood: clamped index + zero-multiplier for out-of-bounds (branchless)
  int   idx9[9];
  float vld9[9];
#pragma unroll
  for (int kk = 0; kk < 9; ++kk) {
    int dy = kk / 3 - 1, dx = kk % 3 - 1;
    int yy = hi + dy, xx = wi + dx;
    bool v = (yy >= 0) && (yy < HW_) && (xx >= 0) && (xx < HW_);
    int yc = min(max(yy, 0), HW_ - 1), xc = min(max(xx, 0), HW_ - 1);
    idx9[kk] = yc * HW_ + xc;
    vld9[kk] = v ? 1.f : 0.f;
  }

  for (int c = 0; c < CIN_; ++c) {
    const float* xc = xb + c * IMG_;
    const float* wbase = wT_off + c * 9 * 32;   // uniform -> scalar loads
#pragma unroll
    for (int kk = 0; kk < 9; ++kk) {
      float xv = xc[idx9[kk]] * vld9[kk];
      const float* wrow = wbase + kk * 32;
#pragma unroll
      for (int oc = 0; oc < 27; ++oc)
        acc[oc] = fmaf(xv, wrow[oc], acc[oc]);
    }
  }

  float* ob = offbuf + bi * (27 * IMG_) + hi * HW_ + wi;
#pragma unroll
  for (int j = 0; j < 9; ++j) {
    ob[j * IMG_]        = acc[j] + b_off[j];
    ob[(9 + j) * IMG_]  = acc[9 + j] + b_off[9 + j];
    float m = acc[18 + j] + b_off[18 + j];
    ob[(18 + j) * IMG_] = 1.f / (1.f + __expf(-m));   // store sigmoid(mask)
  }
}

__global__ __launch_bounds__(256) void dfc_gemm(const float* __restrict__ x,
                                                const float* __restrict__ offbuf,
                                                const float* __restrict__ wT,
                                                float* __restrict__ out) {
  int t = blockIdx.x * 256 + threadIdx.x;
  int wi = t & 127, hi = (t >> 7) & 127, bi = t >> 14;

  float acc[64];
#pragma unroll
  for (int i = 0; i < 64; ++i) acc[i] = 0.f;

  const float* xb = x + bi * (CIN_ * IMG_);
  const float* ob = offbuf + bi * (27 * IMG_) + hi * HW_ + wi;

  for (int j = 0; j < 9; ++j) {
    float o1 = ob[j * IMG_];
    float o2 = ob[(9 + j) * IMG_];
    float mk = ob[(18 + j) * IMG_];

    // absolute sample coords; base grid + per-tap bias: dx = j%3-1, dy = j/3-1
    float px = o1 + (float)(wi + (j % 3) - 1);
    float py = o2 + (float)(hi + (j / 3) - 1);

    float fx = floorf(px), fy = floorf(py);
    int   x0 = (int)fx,   y0 = (int)fy;
    float ax = px - fx, ay = py - fy;       // frac weights toward x0+1 / y0+1
    float bx = 1.f - ax, by = 1.f - ay;

    bool vx0 = (x0 >= 0)  && (x0 < HW_);
    bool vx1 = (x0 >= -1) && (x0 < HW_ - 1);
    bool vy0 = (y0 >= 0)  && (y0 < HW_);
    bool vy1 = (y0 >= -1) && (y0 < HW_ - 1);

    // bilinear corner weights with validity and sigmoid-mask folded in
    float w00 = by * bx * mk * ((vy0 && vx0) ? 1.f : 0.f);
    float w01 = by * ax * mk * ((vy0 && vx1) ? 1.f : 0.f);
    float w10 = ay * bx * mk * ((vy1 && vx0) ? 1.f : 0.f);
    float w11 = ay * ax * mk * ((vy1 && vx1) ? 1.f : 0.f);

    int xc0 = min(max(x0, 0), HW_ - 1), xc1 = min(max(x0 + 1, 0), HW_ - 1);
    int yc0 = min(max(y0, 0), HW_ - 1), yc1 = min(max(y0 + 1, 0), HW_ - 1);
    int i00 = yc0 * HW_ + xc0, i01 = yc0 * HW_ + xc1;
    int i10 = yc1 * HW_ + xc0, i11 = yc1 * HW_ + xc1;

    const float* wj = wT + j * 64;
    for (int c = 0; c < CIN_; ++c) {
      const float* xc = xb + c * IMG_;
      float v = fmaf(w00, xc[i00],
                fmaf(w01, xc[i01],
                fmaf(w10, xc[i10],
                     w11 * xc[i11])));
      const float* wrow = wj + c * 576;     // (c*9+j)*64, uniform -> SGPR broadcast
#pragma unroll
      for (int o = 0; o < 64; ++o)
        acc[o] = fmaf(v, wrow[o], acc[o]);
    }
  }

  float* op = out + bi * (CIN_ * IMG_) + hi * HW_ + wi;
#pragma unroll
  for (int o = 0; o < 64; ++o)
    op[o * IMG_] = acc[o];
}

extern "C" void kernel_launch(void* const* d_in, const int* in_sizes, int n_in,
                              void* d_out, int out_size, void* d_ws, size_t ws_size,
                              hipStream_t stream) {
  const float* x      = (const float*)d_in[0];
  const float* w_off  = (const float*)d_in[1];
  const float* b_off  = (const float*)d_in[2];
  const float* w_conv = (const float*)d_in[3];
  float* out = (float*)d_out;

  char* ws = (char*)d_ws;
  float* wT_conv = (float*)(ws);
  float* wT_off  = (float*)(ws + 147456);
  float* offbuf  = (float*)(ws + 147456 + 73728);

  hipLaunchKernelGGL(xpose_w,  dim3(144), dim3(256), 0, stream, w_off, w_conv, wT_conv, wT_off);
  hipLaunchKernelGGL(off_conv, dim3(512), dim3(256), 0, stream, x, wT_off, b_off, offbuf);
  hipLaunchKernelGGL(dfc_gemm, dim3(512), dim3(256), 0, stream, x, offbuf, wT_conv, out);
}

// Round 2
// 268.482 us; speedup vs baseline: 1.5958x; 1.5958x over previous
//
#include <hip/hip_runtime.h>
#include <math.h>

#define HW_   128
#define CIN_  64
#define IMG_  (HW_ * HW_)       // 16384
#define NB_   8

typedef short  s16x8 __attribute__((ext_vector_type(8)));
typedef float  f32x4 __attribute__((ext_vector_type(4)));

__device__ __forceinline__ float bf2f(short u) {
  union { unsigned i; float f; } v;
  v.i = ((unsigned)(unsigned short)u) << 16;
  return v.f;
}
__device__ __forceinline__ short f2bf(float f) {
  union { float f; unsigned i; } v; v.f = f;
  unsigned r = (v.i + 0x7fffu + ((v.i >> 16) & 1u)) >> 16;   // RNE
  return (short)r;
}

// ws layout (bytes):
//   [0,        36864)    wofb [32][576] bf16 : wofb[m][j*64+c] = w_off[m][c][kh][kw], rows 27..31 = 0
//   [36864,    110592)   wcb  [64][576] bf16 : wcb[o][j*64+c]  = w_conv[o][c*9+j]
//   [110592,   16887808) x_t  [8][128][128][64] bf16 (NHWC)
//   [16887808, 31043584) offbuf [8][27][16384] f32 : o1(0-8), o2(9-17), sigmoid(mask)(18-26)

__global__ __launch_bounds__(256) void prep_w(const float* __restrict__ w_off,
                                              const float* __restrict__ w_conv,
                                              short* __restrict__ wofb,
                                              short* __restrict__ wcb) {
  int t = blockIdx.x * 256 + threadIdx.x;
  if (t < 64 * 576) {
    int o = t / 576, k = t - o * 576;
    int j = k >> 6, c = k & 63;
    wcb[t] = f2bf(w_conv[o * 576 + c * 9 + j]);
  }
  if (t < 32 * 576) {
    int m = t / 576, k = t - m * 576;
    int j = k >> 6, c = k & 63;
    wofb[t] = (m < 27) ? f2bf(w_off[m * 576 + c * 9 + j]) : (short)0;
  }
}

// NCHW f32 -> NHWC bf16 via LDS tile (conflict-free, coalesced both sides)
__global__ __launch_bounds__(256) void xpose_x(const float* __restrict__ x,
                                               short* __restrict__ x_t) {
  __shared__ float lt[64][65];
  int bi  = blockIdx.x >> 8;         // 8 batches x 256 segments
  int hw0 = (blockIdx.x & 255) * 64; // 64 contiguous pixels
  int t = threadIdx.x;
  const float* xb = x + bi * (CIN_ * IMG_) + hw0;
#pragma unroll
  for (int i = 0; i < 16; ++i) {
    int c = i * 4 + (t >> 6), px = t & 63;
    lt[c][px] = xb[c * IMG_ + px];
  }
  __syncthreads();
  short* ob = x_t + (bi * IMG_ + hw0) * 64;
#pragma unroll
  for (int i = 0; i < 16; ++i) {
    int px = i * 4 + (t >> 6), c = t & 63;
    ob[px * 64 + c] = f2bf(lt[c][px]);
  }
}

// offset conv as fused im2col-tile + MFMA: C[32][64px] = wofb[32][576] * tile
__global__ __launch_bounds__(256) void offc_mfma(const short* __restrict__ x_t,
                                                 const short* __restrict__ wofb,
                                                 const float* __restrict__ b_off,
                                                 float* __restrict__ offbuf) {
  __shared__ short tile[2][64][72];   // [px][ch], pitch 72 for bank balance
  int bi  = blockIdx.x >> 8;
  int hw0 = (blockIdx.x & 255) * 64;
  int h   = hw0 >> 7;
  int w0  = hw0 & 127;

  int t   = threadIdx.x;
  int wv  = t >> 6, l = t & 63;
  int col = l & 15, q = l >> 4;
  int px_local = wv * 16 + col;       // 0..63
  int cg = q;                         // 16-channel group

  const short* xb = x_t + bi * (IMG_ * 64);

  f32x4 acc0 = {0.f, 0.f, 0.f, 0.f};
  f32x4 acc1 = {0.f, 0.f, 0.f, 0.f};

  int p = 0;
  for (int j = 0; j < 9; ++j) {
    int dy = j / 3 - 1, dx = j % 3 - 1;
    int hh = h + dy;
    int ww = w0 + px_local + dx;
    s16x8 v0 = {0,0,0,0,0,0,0,0}, v1 = {0,0,0,0,0,0,0,0};
    if (hh >= 0 && hh < HW_ && ww >= 0 && ww < HW_) {
      const short* src = xb + (hh * HW_ + ww) * 64 + cg * 16;
      v0 = *(const s16x8*)(src);
      v1 = *(const s16x8*)(src + 8);
    }
    *(s16x8*)&tile[p][px_local][cg * 16]     = v0;
    *(s16x8*)&tile[p][px_local][cg * 16 + 8] = v1;
    __syncthreads();
#pragma unroll
    for (int ks = 0; ks < 2; ++ks) {
      s16x8 bfrag = *(const s16x8*)&tile[p][px_local][ks * 32 + q * 8];
      s16x8 a0 = *(const s16x8*)(wofb + (col)      * 576 + j * 64 + ks * 32 + q * 8);
      s16x8 a1 = *(const s16x8*)(wofb + (16 + col) * 576 + j * 64 + ks * 32 + q * 8);
      acc0 = __builtin_amdgcn_mfma_f32_16x16x32_bf16(a0, bfrag, acc0, 0, 0, 0);
      acc1 = __builtin_amdgcn_mfma_f32_16x16x32_bf16(a1, bfrag, acc1, 0, 0, 0);
    }
    p ^= 1;
  }

  // epilogue: ch = ms*16 + q*4 + r ; +bias ; sigmoid for ch>=18 ; skip ch>=27
  float* ob = offbuf + bi * (27 * IMG_) + hw0 + px_local;
#pragma unroll
  for (int r = 0; r < 4; ++r) {
    int ch = q * 4 + r;
    float v = acc0[r] + b_off[ch];
    if (ch >= 18) v = 1.f / (1.f + __expf(-v));
    ob[ch * IMG_] = v;
  }
#pragma unroll
  for (int r = 0; r < 4; ++r) {
    int ch = 16 + q * 4 + r;
    if (ch < 27) {
      float v = acc1[r] + b_off[ch];
      if (ch >= 18) v = 1.f / (1.f + __expf(-v));
      ob[ch * IMG_] = v;
    }
  }
}

// fused deformable sampling -> bf16 LDS tile -> MFMA GEMM (64 out ch)
__global__ __launch_bounds__(256) void dfc_mfma(const short* __restrict__ x_t,
                                                const float* __restrict__ offbuf,
                                                const short* __restrict__ wcb,
                                                float* __restrict__ out) {
  __shared__ short tile[2][64][72];
  int bi  = blockIdx.x >> 8;
  int hw0 = (blockIdx.x & 255) * 64;
  int h   = hw0 >> 7;
  int w0  = hw0 & 127;

  int t   = threadIdx.x;
  int wv  = t >> 6, l = t & 63;
  int col = l & 15, q = l >> 4;
  int px_local = wv * 16 + col;
  int cg = q;

  const short* xb = x_t + bi * (IMG_ * 64);
  const float* ob = offbuf + bi * (27 * IMG_) + hw0 + px_local;

  f32x4 acc[4];
#pragma unroll
  for (int ms = 0; ms < 4; ++ms) acc[ms] = (f32x4){0.f, 0.f, 0.f, 0.f};

  int p = 0;
  for (int j = 0; j < 9; ++j) {
    float o1 = ob[j * IMG_];
    float o2 = ob[(9 + j) * IMG_];
    float mk = ob[(18 + j) * IMG_];

    float pxf = o1 + (float)(w0 + px_local + (j % 3) - 1);
    float pyf = o2 + (float)(h + (j / 3) - 1);

    float fx = floorf(pxf), fy = floorf(pyf);
    int   x0 = (int)fx,   y0 = (int)fy;
    float ax = pxf - fx, ay = pyf - fy;
    float bx = 1.f - ax, by = 1.f - ay;

    bool vx0 = (x0 >= 0)  && (x0 < HW_);
    bool vx1 = (x0 >= -1) && (x0 < HW_ - 1);
    bool vy0 = (y0 >= 0)  && (y0 < HW_);
    bool vy1 = (y0 >= -1) && (y0 < HW_ - 1);

    float w00 = by * bx * mk * ((vy0 && vx0) ? 1.f : 0.f);
    float w01 = by * ax * mk * ((vy0 && vx1) ? 1.f : 0.f);
    float w10 = ay * bx * mk * ((vy1 && vx0) ? 1.f : 0.f);
    float w11 = ay * ax * mk * ((vy1 && vx1) ? 1.f : 0.f);

    int xc0 = min(max(x0, 0), HW_ - 1), xc1 = min(max(x0 + 1, 0), HW_ - 1);
    int yc0 = min(max(y0, 0), HW_ - 1), yc1 = min(max(y0 + 1, 0), HW_ - 1);

    const short* p00 = xb + (yc0 * HW_ + xc0) * 64 + cg * 16;
    const short* p01 = xb + (yc0 * HW_ + xc1) * 64 + cg * 16;
    const short* p10 = xb + (yc1 * HW_ + xc0) * 64 + cg * 16;
    const short* p11 = xb + (yc1 * HW_ + xc1) * 64 + cg * 16;

    s16x8 c00a = *(const s16x8*)(p00),     c00b = *(const s16x8*)(p00 + 8);
    s16x8 c01a = *(const s16x8*)(p01),     c01b = *(const s16x8*)(p01 + 8);
    s16x8 c10a = *(const s16x8*)(p10),     c10b = *(const s16x8*)(p10 + 8);
    s16x8 c11a = *(const s16x8*)(p11),     c11b = *(const s16x8*)(p11 + 8);

    s16x8 ya, yb2;
#pragma unroll
    for (int i = 0; i < 8; ++i) {
      float v = w00 * bf2f(c00a[i]) + w01 * bf2f(c01a[i])
              + w10 * bf2f(c10a[i]) + w11 * bf2f(c11a[i]);
      ya[i] = f2bf(v);
    }
#pragma unroll
    for (int i = 0; i < 8; ++i) {
      float v = w00 * bf2f(c00b[i]) + w01 * bf2f(c01b[i])
              + w10 * bf2f(c10b[i]) + w11 * bf2f(c11b[i]);
      yb2[i] = f2bf(v);
    }

    *(s16x8*)&tile[p][px_local][cg * 16]     = ya;
    *(s16x8*)&tile[p][px_local][cg * 16 + 8] = yb2;
    __syncthreads();

#pragma unroll
    for (int ks = 0; ks < 2; ++ks) {
      s16x8 bfrag = *(const s16x8*)&tile[p][px_local][ks * 32 + q * 8];
#pragma unroll
      for (int ms = 0; ms < 4; ++ms) {
        s16x8 afrag = *(const s16x8*)(wcb + (ms * 16 + col) * 576 + j * 64 + ks * 32 + q * 8);
        acc[ms] = __builtin_amdgcn_mfma_f32_16x16x32_bf16(afrag, bfrag, acc[ms], 0, 0, 0);
      }
    }
    p ^= 1;
  }

  float* op = out + bi * (CIN_ * IMG_) + hw0 + px_local;
#pragma unroll
  for (int ms = 0; ms < 4; ++ms)
#pragma unroll
    for (int r = 0; r < 4; ++r)
      op[(ms * 16 + q * 4 + r) * IMG_] = acc[ms][r];
}

extern "C" void kernel_launch(void* const* d_in, const int* in_sizes, int n_in,
                              void* d_out, int out_size, void* d_ws, size_t ws_size,
                              hipStream_t stream) {
  const float* x      = (const float*)d_in[0];
  const float* w_off  = (const float*)d_in[1];
  const float* b_off  = (const float*)d_in[2];
  const float* w_conv = (const float*)d_in[3];
  float* out = (float*)d_out;

  char* ws = (char*)d_ws;
  short* wofb   = (short*)(ws);
  short* wcb    = (short*)(ws + 36864);
  short* x_t    = (short*)(ws + 110592);
  float* offbuf = (float*)(ws + 16887808);

  hipLaunchKernelGGL(prep_w,    dim3(144),  dim3(256), 0, stream, w_off, w_conv, wofb, wcb);
  hipLaunchKernelGGL(xpose_x,   dim3(2048), dim3(256), 0, stream, x, x_t);
  hipLaunchKernelGGL(offc_mfma, dim3(2048), dim3(256), 0, stream, x_t, wofb, b_off, offbuf);
  hipLaunchKernelGGL(dfc_mfma,  dim3(2048), dim3(256), 0, stream, x_t, offbuf, wcb, out);
}